// Round 4
// baseline (200.748 us; speedup 1.0000x reference)
//
#include <hip/hip_runtime.h>

#define NCLS  256
#define NSMP  32
#define DIM   2048
#define DV    (DIM / 4)        // 512 float4 columns per sample
#define SPLIT 2                // column-chunks per class
#define CHUNK (DV / SPLIT)     // 256 float4 columns per block
#define BLK   256              // one thread per float4 column in the chunk
#define ROWS  264              // padded LDS row stride (floats), 16B-aligned
#define PF    8                // neg prefetch depth

// main kernel: per (class, chunk) partial d^2 sums -> ws
__global__ __launch_bounds__(BLK, 2)
void ccl_partial(const float* __restrict__ emb,
                 float* __restrict__ ws_pos,
                 float* __restrict__ ws_neg) {
    const int c   = blockIdx.x;
    const int h   = blockIdx.y;
    const int tid = threadIdx.x;

    __shared__ float part[NSMP * ROWS];   // ~33 KB

    const float* base = emb + (size_t)c * 2 * NSMP * DIM + (size_t)h * (CHUNK * 4);
    const float4* pos = (const float4*)base;
    const float4* neg = (const float4*)(base + (size_t)NSMP * DIM);

    // ---- cache all 32 pos samples of this thread's column
    float4 x[NSMP];
    #pragma unroll
    for (int i = 0; i < NSMP; ++i) x[i] = pos[(size_t)i * DV + tid];

    // ---- anchor (this column) = mean, in-register
    float4 a = make_float4(0.f, 0.f, 0.f, 0.f);
    #pragma unroll
    for (int i = 0; i < NSMP; ++i) {
        a.x += x[i].x; a.y += x[i].y; a.z += x[i].z; a.w += x[i].w;
    }
    const float inv = 1.0f / (float)NSMP;
    a.x *= inv; a.y *= inv; a.z *= inv; a.w *= inv;

    // ---- prefetch first PF neg samples
    float4 nb[PF];
    #pragma unroll
    for (int j = 0; j < PF; ++j) nb[j] = neg[(size_t)j * DV + tid];

    // ---- pos d^2 partials -> LDS
    #pragma unroll
    for (int i = 0; i < NSMP; ++i) {
        float dx = x[i].x - a.x, dy = x[i].y - a.y;
        float dz = x[i].z - a.z, dw = x[i].w - a.w;
        part[i * ROWS + tid] = dx * dx + dy * dy + dz * dz + dw * dw;
    }
    __syncthreads();

    // ---- transpose-reduce pos: 8 threads per sample
    const int s  = tid >> 3;
    const int c8 = tid & 7;
    {
        float sum = 0.f;
        #pragma unroll
        for (int k = 0; k < 8; ++k) {
            float4 v = *(const float4*)&part[s * ROWS + c8 * 4 + k * 32];
            sum += v.x + v.y + v.z + v.w;
        }
        #pragma unroll
        for (int off = 4; off >= 1; off >>= 1) sum += __shfl_xor(sum, off, 64);
        if (c8 == 0) atomicAdd(&ws_pos[c * NSMP + s], sum);
    }
    __syncthreads();   // part[] reused for neg

    // ---- neg d^2 partials with rolling prefetch
    #pragma unroll
    for (int i = 0; i < NSMP; ++i) {
        float4 n = nb[i & (PF - 1)];
        if (i + PF < NSMP) nb[i & (PF - 1)] = neg[(size_t)(i + PF) * DV + tid];
        float dx = n.x - a.x, dy = n.y - a.y;
        float dz = n.z - a.z, dw = n.w - a.w;
        part[i * ROWS + tid] = dx * dx + dy * dy + dz * dz + dw * dw;
    }
    __syncthreads();

    // ---- transpose-reduce neg
    {
        float sum = 0.f;
        #pragma unroll
        for (int k = 0; k < 8; ++k) {
            float4 v = *(const float4*)&part[s * ROWS + c8 * 4 + k * 32];
            sum += v.x + v.y + v.z + v.w;
        }
        #pragma unroll
        for (int off = 4; off >= 1; off >>= 1) sum += __shfl_xor(sum, off, 64);
        if (c8 == 0) atomicAdd(&ws_neg[c * NSMP + s], sum);
    }
}

// finalize: one block; thread c = class c
__global__ __launch_bounds__(NCLS)
void ccl_final(const float* __restrict__ ws_pos,
               const float* __restrict__ ws_neg,
               const float* __restrict__ margin_p,
               float* __restrict__ out) {
    const int c    = threadIdx.x;
    const int wave = c >> 6;
    const int lane = c & 63;
    __shared__ float red[NCLS / 64];

    const float margin = margin_p[0];

    float nd = 3.4e38f;
    #pragma unroll
    for (int i = 0; i < NSMP; ++i) nd = fminf(nd, ws_neg[c * NSMP + i]);
    const float an = sqrtf(nd);

    float l = 0.f;
    #pragma unroll
    for (int i = 0; i < NSMP; ++i) {
        float ap = sqrtf(ws_pos[c * NSMP + i]);
        float v  = fmaxf(ap - an + margin, 0.f);
        l += v * v;
    }

    #pragma unroll
    for (int off = 32; off >= 1; off >>= 1) l += __shfl_xor(l, off, 64);
    if (lane == 0) red[wave] = l;
    __syncthreads();
    if (c == 0) {
        float t = 0.f;
        #pragma unroll
        for (int w = 0; w < NCLS / 64; ++w) t += red[w];
        out[0] = t * (1.0f / (float)NCLS);
    }
}

extern "C" void kernel_launch(void* const* d_in, const int* in_sizes, int n_in,
                              void* d_out, int out_size, void* d_ws, size_t ws_size,
                              hipStream_t stream) {
    const float* emb    = (const float*)d_in[0];
    // d_in[1] = target (unused by the reference)
    const float* margin = (const float*)d_in[2];
    float* out = (float*)d_out;

    float* ws_pos = (float*)d_ws;                    // 256*32 floats
    float* ws_neg = ws_pos + NCLS * NSMP;            // 256*32 floats

    hipMemsetAsync(d_ws, 0, 2 * NCLS * NSMP * sizeof(float), stream);

    dim3 grid(NCLS, SPLIT);
    ccl_partial<<<grid, BLK, 0, stream>>>(emb, ws_pos, ws_neg);
    ccl_final<<<1, NCLS, 0, stream>>>(ws_pos, ws_neg, margin, out);
}